// Round 3
// baseline (387.146 us; speedup 1.0000x reference)
//
#include <hip/hip_runtime.h>
#include <cstdint>
#include <cstddef>

#define SEQL   2048
#define DMODEL 1024
#define NHEADS 16
#define DHEAD  64
#define MROWS  4096   // BATCH * SEQ

typedef __attribute__((ext_vector_type(8))) short short8;   // 8 bf16 (4 VGPRs)
typedef __attribute__((ext_vector_type(4))) float f32x4;    // MFMA 16x16 C/D

__device__ __forceinline__ unsigned short f2bf(float x) {
  unsigned int u = __float_as_uint(x);
  u += 0x7fffu + ((u >> 16) & 1u);   // round-to-nearest-even
  return (unsigned short)(u >> 16);
}
__device__ __forceinline__ float bf2f(unsigned short u) {
  return __uint_as_float(((unsigned int)u) << 16);
}
// load 8 contiguous fp32, round to 8 bf16
__device__ __forceinline__ short8 cvt8(const float* __restrict__ p) {
  const float4 lo = *(const float4*)p;
  const float4 hi = *(const float4*)(p + 4);
  short8 v;
  v[0] = (short)f2bf(lo.x); v[1] = (short)f2bf(lo.y);
  v[2] = (short)f2bf(lo.z); v[3] = (short)f2bf(lo.w);
  v[4] = (short)f2bf(hi.x); v[5] = (short)f2bf(hi.y);
  v[6] = (short)f2bf(hi.z); v[7] = (short)f2bf(hi.w);
  return v;
}

// ---------------------------------------------------------------------------
// QKV projection: C[m][n] = sum_k A[m][k] * W[n][k]
// A fp32 [M][K], W fp32 [N][K], C bf16 [M][N].  128x128 tile, BK=32,
// 256 thr = 4 waves, each wave 64x64 via 4x4 16x16x32 MFMA.
// blockIdx.z selects (W,C) pair.
// ---------------------------------------------------------------------------
__global__ __launch_bounds__(256) void gemm_qkv(
    const float* __restrict__ A,
    const float* __restrict__ W0, const float* __restrict__ W1,
    const float* __restrict__ W2,
    unsigned short* __restrict__ C0, unsigned short* __restrict__ C1,
    unsigned short* __restrict__ C2,
    int Mda, int Nda, int Kda) {
  const float* W;
  unsigned short* C;
  if (blockIdx.z == 0)      { W = W0; C = C0; }
  else if (blockIdx.z == 1) { W = W1; C = C1; }
  else                      { W = W2; C = C2; }

  __shared__ __attribute__((aligned(16))) unsigned short As[128 * 32];
  __shared__ __attribute__((aligned(16))) unsigned short Bs[128 * 32];

  const int t = threadIdx.x;
  const int m0 = blockIdx.y * 128, n0 = blockIdx.x * 128;
  const int w = t >> 6, lane = t & 63;
  const int l15 = lane & 15, quad = lane >> 4;
  const int wm = (w >> 1) * 64, wn = (w & 1) * 64;

  const int r1 = t >> 2,         c1 = (t & 3) * 8;
  const int r2 = (t + 256) >> 2, c2 = (t & 3) * 8;

  f32x4 acc[4][4] = {};

  for (int k0 = 0; k0 < Kda; k0 += 32) {
    __syncthreads();
    *(short8*)(&As[r1 * 32 + c1]) = cvt8(A + (size_t)(m0 + r1) * Kda + k0 + c1);
    *(short8*)(&As[r2 * 32 + c2]) = cvt8(A + (size_t)(m0 + r2) * Kda + k0 + c2);
    *(short8*)(&Bs[r1 * 32 + c1]) = cvt8(W + (size_t)(n0 + r1) * Kda + k0 + c1);
    *(short8*)(&Bs[r2 * 32 + c2]) = cvt8(W + (size_t)(n0 + r2) * Kda + k0 + c2);
    __syncthreads();

    short8 af[4], bfr[4];
#pragma unroll
    for (int i = 0; i < 4; ++i)
      af[i] = *(const short8*)(&As[(wm + i * 16 + l15) * 32 + quad * 8]);
#pragma unroll
    for (int j = 0; j < 4; ++j)
      bfr[j] = *(const short8*)(&Bs[(wn + j * 16 + l15) * 32 + quad * 8]);
#pragma unroll
    for (int i = 0; i < 4; ++i)
#pragma unroll
      for (int j = 0; j < 4; ++j)
        acc[i][j] = __builtin_amdgcn_mfma_f32_16x16x32_bf16(af[i], bfr[j], acc[i][j], 0, 0, 0);
  }

#pragma unroll
  for (int i = 0; i < 4; ++i)
#pragma unroll
    for (int j = 0; j < 4; ++j)
#pragma unroll
      for (int r = 0; r < 4; ++r) {
        int row = m0 + wm + i * 16 + quad * 4 + r;
        int col = n0 + wn + j * 16 + l15;
        C[(size_t)row * Nda + col] = f2bf(acc[i][j][r]);
      }
}

// ---------------------------------------------------------------------------
// Output projection: A bf16 [M][K], W fp32 [N][K], C fp32 [M][N]
// ---------------------------------------------------------------------------
__global__ __launch_bounds__(256) void gemm_out(
    const unsigned short* __restrict__ A,
    const float* __restrict__ W,
    float* __restrict__ C,
    int Mda, int Nda, int Kda) {
  __shared__ __attribute__((aligned(16))) unsigned short As[128 * 32];
  __shared__ __attribute__((aligned(16))) unsigned short Bs[128 * 32];

  const int t = threadIdx.x;
  const int m0 = blockIdx.y * 128, n0 = blockIdx.x * 128;
  const int w = t >> 6, lane = t & 63;
  const int l15 = lane & 15, quad = lane >> 4;
  const int wm = (w >> 1) * 64, wn = (w & 1) * 64;

  const int r1 = t >> 2,         c1 = (t & 3) * 8;
  const int r2 = (t + 256) >> 2, c2 = (t & 3) * 8;

  f32x4 acc[4][4] = {};

  for (int k0 = 0; k0 < Kda; k0 += 32) {
    __syncthreads();
    *(float4*)(&As[(size_t)r1 * 32 + c1]) = *(const float4*)(A + (size_t)(m0 + r1) * Kda + k0 + c1);
    *(float4*)(&As[(size_t)r2 * 32 + c2]) = *(const float4*)(A + (size_t)(m0 + r2) * Kda + k0 + c2);
    *(short8*)(&Bs[r1 * 32 + c1]) = cvt8(W + (size_t)(n0 + r1) * Kda + k0 + c1);
    *(short8*)(&Bs[r2 * 32 + c2]) = cvt8(W + (size_t)(n0 + r2) * Kda + k0 + c2);
    __syncthreads();

    short8 af[4], bfr[4];
#pragma unroll
    for (int i = 0; i < 4; ++i)
      af[i] = *(const short8*)(&As[(wm + i * 16 + l15) * 32 + quad * 8]);
#pragma unroll
    for (int j = 0; j < 4; ++j)
      bfr[j] = *(const short8*)(&Bs[(wn + j * 16 + l15) * 32 + quad * 8]);
#pragma unroll
    for (int i = 0; i < 4; ++i)
#pragma unroll
      for (int j = 0; j < 4; ++j)
        acc[i][j] = __builtin_amdgcn_mfma_f32_16x16x32_bf16(af[i], bfr[j], acc[i][j], 0, 0, 0);
  }

#pragma unroll
  for (int i = 0; i < 4; ++i)
#pragma unroll
    for (int j = 0; j < 4; ++j)
#pragma unroll
      for (int r = 0; r < 4; ++r) {
        int row = m0 + wm + i * 16 + quad * 4 + r;
        int col = n0 + wn + j * 16 + l15;
        C[(size_t)row * Nda + col] = acc[i][j][r];
      }
}

// ---------------------------------------------------------------------------
// In-place RoPE on bf16 Q and K flat [M][1024]: pairs (h*64+2i, h*64+2i+1)
// ---------------------------------------------------------------------------
__global__ __launch_bounds__(256) void rope_inplace(unsigned short* __restrict__ Q,
                                                    unsigned short* __restrict__ K,
                                                    const int* __restrict__ pos_arr) {
  const int row = blockIdx.x;            // b*SEQ + s
  const int s = row & (SEQL - 1);
  const float pos = (float)pos_arr[s];
  // log2(10000)/32 = 0.4152410118609203
  for (int p = threadIdx.x; p < 512; p += 256) {
    const int h = p >> 5, i = p & 31;
    float inv = exp2f((float)i * -0.4152410118609203f);
    float ang = pos * inv;
    float sn, cs;
    sincosf(ang, &sn, &cs);
    size_t base = (size_t)row * DMODEL + h * DHEAD + 2 * i;
    float e = bf2f(Q[base]), o = bf2f(Q[base + 1]);
    Q[base]     = f2bf(e * cs - o * sn);
    Q[base + 1] = f2bf(e * sn + o * cs);
    e = bf2f(K[base]); o = bf2f(K[base + 1]);
    K[base]     = f2bf(e * cs - o * sn);
    K[base + 1] = f2bf(e * sn + o * cs);
  }
}

// ---------------------------------------------------------------------------
// Causal flash attention (bf16 in/out). Block = 64 q rows (4 waves x 16),
// kv tiles of 32. K and V tiles staged in LDS (shared by the 4 waves);
// V stored transposed. Uniform kv trip count so __syncthreads() is legal.
// Output written IN PLACE into Q (each block reads its Q rows into registers
// at kernel start and is the only writer of those (row, head-col) elements).
// ---------------------------------------------------------------------------
#define KS_STRIDE 72   // shorts; 144 B rows -> 16B aligned
#define VS_STRIDE 40   // shorts; 80 B rows  -> 16B aligned

__global__ __launch_bounds__(256) void attn_kernel(const unsigned short* __restrict__ Kf,
                                                   const unsigned short* __restrict__ Vf,
                                                   unsigned short* __restrict__ Qio) {
  __shared__ __attribute__((aligned(16))) unsigned short Ks[32 * KS_STRIDE];
  __shared__ __attribute__((aligned(16))) unsigned short Vs[64 * VS_STRIDE];
  __shared__ __attribute__((aligned(16))) unsigned short Pl[4][16 * 32];

  const int bh = blockIdx.y;
  const int b = bh >> 4, h = bh & 15;
  const int t = threadIdx.x;
  const int w = t >> 6;
  const int lane = t & 63;
  const int l15 = lane & 15, quad = lane >> 4;
  const int qw = blockIdx.x * 64 + w * 16;
  const float scale = 0.125f;  // 1/sqrt(64)

  const unsigned short* qp = Qio + ((size_t)(b * SEQL + qw + l15)) * DMODEL + h * DHEAD + quad * 8;
  const short8 aq0 = *(const short8*)(qp);
  const short8 aq1 = *(const short8*)(qp + 32);

  f32x4 o0 = {0.f, 0.f, 0.f, 0.f}, o1 = o0, o2 = o0, o3 = o0;
  float mr[4] = {-1e30f, -1e30f, -1e30f, -1e30f};
  float lr[4] = {0.f, 0.f, 0.f, 0.f};

  const int kvr = t >> 3, dcol = (t & 7) * 8;
  const unsigned short* kg = Kf + ((size_t)(b * SEQL + kvr)) * DMODEL + h * DHEAD + dcol;
  const unsigned short* vg = Vf + ((size_t)(b * SEQL + kvr)) * DMODEL + h * DHEAD + dcol;

  const int kv_hi = blockIdx.x * 64 + 63;   // uniform across the block
  for (int kv0 = 0; kv0 <= kv_hi; kv0 += 32) {
    __syncthreads();   // previous iteration's LDS reads complete
    *(short8*)(&Ks[kvr * KS_STRIDE + dcol]) = *(const short8*)(kg + (size_t)kv0 * DMODEL);
    short8 v8 = *(const short8*)(vg + (size_t)kv0 * DMODEL);
#pragma unroll
    for (int e = 0; e < 8; ++e)
      Vs[(dcol + e) * VS_STRIDE + kvr] = (unsigned short)v8[e];   // transposed store
    __syncthreads();

    const short8 bk00 = *(const short8*)(&Ks[l15 * KS_STRIDE + quad * 8]);
    const short8 bk01 = *(const short8*)(&Ks[l15 * KS_STRIDE + 32 + quad * 8]);
    const short8 bk10 = *(const short8*)(&Ks[(16 + l15) * KS_STRIDE + quad * 8]);
    const short8 bk11 = *(const short8*)(&Ks[(16 + l15) * KS_STRIDE + 32 + quad * 8]);
    f32x4 z = {0.f, 0.f, 0.f, 0.f};
    f32x4 s0 = __builtin_amdgcn_mfma_f32_16x16x32_bf16(aq0, bk00, z, 0, 0, 0);
    s0 = __builtin_amdgcn_mfma_f32_16x16x32_bf16(aq1, bk01, s0, 0, 0, 0);
    f32x4 s1 = __builtin_amdgcn_mfma_f32_16x16x32_bf16(aq0, bk10, z, 0, 0, 0);
    s1 = __builtin_amdgcn_mfma_f32_16x16x32_bf16(aq1, bk11, s1, 0, 0, 0);

    float al[4], p0v[4], p1v[4];
#pragma unroll
    for (int r = 0; r < 4; ++r) {
      const int q = qw + quad * 4 + r;
      float v0 = s0[r] * scale; if (kv0 + l15 > q)      v0 = -1e30f;
      float v1 = s1[r] * scale; if (kv0 + 16 + l15 > q) v1 = -1e30f;
      float rm = fmaxf(v0, v1);
      rm = fmaxf(rm, __shfl_xor(rm, 1));
      rm = fmaxf(rm, __shfl_xor(rm, 2));
      rm = fmaxf(rm, __shfl_xor(rm, 4));
      rm = fmaxf(rm, __shfl_xor(rm, 8));
      const float mn = fmaxf(mr[r], rm);
      const float a = __expf(mr[r] - mn);
      mr[r] = mn;
      const float p0 = __expf(v0 - mn);
      const float p1 = __expf(v1 - mn);
      float sum = p0 + p1;
      sum += __shfl_xor(sum, 1);
      sum += __shfl_xor(sum, 2);
      sum += __shfl_xor(sum, 4);
      sum += __shfl_xor(sum, 8);
      lr[r] = lr[r] * a + sum;
      al[r] = a; p0v[r] = p0; p1v[r] = p1;
    }
#pragma unroll
    for (int r = 0; r < 4; ++r) {
      o0[r] *= al[r]; o1[r] *= al[r]; o2[r] *= al[r]; o3[r] *= al[r];
      Pl[w][(quad * 4 + r) * 32 + l15]      = f2bf(p0v[r]);
      Pl[w][(quad * 4 + r) * 32 + 16 + l15] = f2bf(p1v[r]);
    }
    // same-wave DS ordering: drain writes before cross-lane LDS read
    asm volatile("s_waitcnt lgkmcnt(0)" ::: "memory");
    const short8 ap  = *(const short8*)(&Pl[w][l15 * 32 + quad * 8]);
    const short8 bv0 = *(const short8*)(&Vs[l15 * VS_STRIDE + quad * 8]);
    const short8 bv1 = *(const short8*)(&Vs[(16 + l15) * VS_STRIDE + quad * 8]);
    const short8 bv2 = *(const short8*)(&Vs[(32 + l15) * VS_STRIDE + quad * 8]);
    const short8 bv3 = *(const short8*)(&Vs[(48 + l15) * VS_STRIDE + quad * 8]);
    o0 = __builtin_amdgcn_mfma_f32_16x16x32_bf16(ap, bv0, o0, 0, 0, 0);
    o1 = __builtin_amdgcn_mfma_f32_16x16x32_bf16(ap, bv1, o1, 0, 0, 0);
    o2 = __builtin_amdgcn_mfma_f32_16x16x32_bf16(ap, bv2, o2, 0, 0, 0);
    o3 = __builtin_amdgcn_mfma_f32_16x16x32_bf16(ap, bv3, o3, 0, 0, 0);
  }

  float il[4];
#pragma unroll
  for (int r = 0; r < 4; ++r) il[r] = 1.f / lr[r];
  unsigned short* ob = Qio + ((size_t)(b * SEQL + qw + quad * 4)) * DMODEL + h * DHEAD + l15;
#pragma unroll
  for (int r = 0; r < 4; ++r) {
    unsigned short* orow = ob + (size_t)r * DMODEL;
    orow[0]  = f2bf(o0[r] * il[r]);
    orow[16] = f2bf(o1[r] * il[r]);
    orow[32] = f2bf(o2[r] * il[r]);
    orow[48] = f2bf(o3[r] * il[r]);
  }
}

// ---------------------------------------------------------------------------
extern "C" void kernel_launch(void* const* d_in, const int* in_sizes, int n_in,
                              void* d_out, int out_size, void* d_ws, size_t ws_size,
                              hipStream_t stream) {
  (void)in_sizes; (void)n_in; (void)out_size; (void)ws_size;
  const float* x  = (const float*)d_in[0];
  const int* tpos = (const int*)d_in[1];
  const float* Wq = (const float*)d_in[2];
  const float* Wk = (const float*)d_in[3];
  const float* Wv = (const float*)d_in[4];
  const float* Wo = (const float*)d_in[5];
  float* out      = (float*)d_out;

  char* ws = (char*)d_ws;
  const size_t TS = (size_t)MROWS * DMODEL * sizeof(unsigned short);  // 8 MB
  unsigned short* Qf = (unsigned short*)(ws);
  unsigned short* Kf = (unsigned short*)(ws + TS);
  unsigned short* Vf = (unsigned short*)(ws + 2 * TS);
  // total workspace use: 24 MB (bf16 Q,K,V; attn output reuses Qf)

  // Q,K,V projections (fp32 in, bf16 out; one launch, z selects weight/output)
  gemm_qkv<<<dim3(8, 32, 3), 256, 0, stream>>>(x, Wq, Wk, Wv, Qf, Kf, Vf, MROWS, DMODEL, DMODEL);
  // RoPE in place on Q,K (bf16)
  rope_inplace<<<dim3(MROWS), 256, 0, stream>>>(Qf, Kf, tpos);
  // causal flash attention; output written in place into Qf (bf16)
  attn_kernel<<<dim3(SEQL / 64, NHEADS * 2), 256, 0, stream>>>(Kf, Vf, Qf);
  // output projection (bf16 A, fp32 W, fp32 out)
  gemm_out<<<dim3(8, 32, 1), 256, 0, stream>>>(Qf, Wo, out, MROWS, DMODEL, DMODEL);
}